// Round 3
// baseline (480.643 us; speedup 1.0000x reference)
//
#include <hip/hip_runtime.h>

// Problem constants (fixed by reference)
#define CI    16
#define CO    16
#define TAPS  9      // 3x3
#define HID   256
#define KPAD  288    // 256 + 32; k==256 row carries b2, k>256 zero
#define NKK   9      // KPAD/32 MFMA K-steps
#define NCH   144    // CI*TAPS columns per output channel
#define IMGH  128
#define IMGW  128
#define HSTR  296    // shH row stride (288 + 8 bf16 pad -> <=2-way LDS conflicts)

typedef float f32x4  __attribute__((ext_vector_type(4)));
typedef short bf16x8 __attribute__((ext_vector_type(8)));

__device__ __host__ __forceinline__ short f2bf(float f) {
  union { float f; unsigned u; } c; c.f = f;
  unsigned b = c.u + 0x7FFFu + ((c.u >> 16) & 1u);   // RNE
  return (short)(b >> 16);
}

// ---------------------------------------------------------------------------
// Prep: W2 [256][2304] fp32 (+ b2[2304]) -> W2b [o][kk][n:144][k:32] bf16,
// K padded to 288 (row 256 = b2, rows 257..287 = 0).
// ---------------------------------------------------------------------------
__global__ void prep_w2(const float* __restrict__ W2, const float* __restrict__ b2,
                        short* __restrict__ W2b) {
  __shared__ float tile[32][65];
  const int kk = blockIdx.x % NKK;
  const int colbase = (blockIdx.x / NKK) * 64;
  const int tid = threadIdx.x;

  for (int e = tid; e < 2048; e += 256) {
    int klr = e >> 6;          // 0..31
    int cc  = e & 63;
    int col = colbase + cc;
    float v;
    if (kk < 8) v = W2[(kk * 32 + klr) * (CO * NCH) + col];
    else        v = (klr == 0) ? b2[col] : 0.f;
    tile[klr][cc] = v;
  }
  __syncthreads();
  for (int e = tid; e < 2048; e += 256) {
    int cc = e >> 5;           // 0..63
    int kl = e & 31;
    int col = colbase + cc;
    int o = col / NCH;
    int n = col - o * NCH;
    W2b[(((o * NKK + kk) * NCH + n) << 5) + kl] = f2bf(tile[kl][cc]);
  }
}

// ---------------------------------------------------------------------------
// One N-half of the per-channel GEMM: columns [NB, NB+NC) of the 9 n-tiles.
// acc[4][NC] stays <= 80 regs so the unified VGPR+AGPR file never spills.
// Partial patch contraction folds straight into P[16].
// ---------------------------------------------------------------------------
template<int NB, int NC>
__device__ __forceinline__ void gemm_half(const short* __restrict__ Bl,
                                          const short* shHp,
                                          const float* shSlab,
                                          float* P,
                                          int c15, int quad, int x0) {
  f32x4 acc[4][NC];
  #pragma unroll
  for (int ms = 0; ms < 4; ++ms)
    #pragma unroll
    for (int j = 0; j < NC; ++j)
      acc[ms][j] = (f32x4){0.f, 0.f, 0.f, 0.f};

  bf16x8 bcur = *(const bf16x8*)&Bl[NB << 9];
  for (int kk = 0; kk < NKK; ++kk) {
    bf16x8 af[4];
    #pragma unroll
    for (int ms = 0; ms < 4; ++ms)   // A: rows = pixels, ds_read_b128
      af[ms] = *(const bf16x8*)&shHp[(ms * 16 + c15) * HSTR + kk * 32 + quad * 8];
    #pragma unroll
    for (int j = 0; j < NC; ++j) {
      int f = kk * 9 + NB + j;
      // next frag in this half: same kk next n, else next kk first n, else stay
      int fn = (j < NC - 1) ? (f + 1) : ((kk < NKK - 1) ? (f + 9 - (NC - 1)) : f);
      bf16x8 bnext = *(const bf16x8*)&Bl[fn << 9];
      #pragma unroll
      for (int ms = 0; ms < 4; ++ms)
        acc[ms][j] = __builtin_amdgcn_mfma_f32_16x16x32_bf16(
            af[ms], bcur, acc[ms][j], 0, 0, 0);
      bcur = bnext;
    }
  }

  // partial epilogue: contract this half's columns with the patch slab
  #pragma unroll
  for (int j = 0; j < NC; ++j) {
    int n15 = (NB + j) * 16 + c15;    // 0..143
    int i = n15 / 9;
    int q = n15 - i * 9;              // tap: dyr = q/3, dx = q%3
    int dyr = q / 3;
    int poff = (i * 3 + dyr) * 130 + (q - dyr * 3) + x0 + quad * 4;
    #pragma unroll
    for (int ms = 0; ms < 4; ++ms)
      #pragma unroll
      for (int r = 0; r < 4; ++r)
        P[ms * 4 + r] = fmaf(acc[ms][j][r], shSlab[poff + ms * 16 + r], P[ms * 4 + r]);
  }
}

// ---------------------------------------------------------------------------
// Main fused kernel. One block = 64 consecutive pixels of one image row.
// 4 waves; wave w computes output channels {w, w+4, w+8, w+12} for all 64
// pixels via MFMA 16x16x32 bf16 (M=pixels, N=144 per channel, K=288).
// N split 5+4 across two K-loop passes to keep acc <= 80 regs (no spill).
// grid = 4 batches * 128 rows * 2 half-rows = 1024 blocks x 256 threads.
// ---------------------------------------------------------------------------
__global__ __launch_bounds__(256, 2)
void ngconv_main(const float* __restrict__ in, const float* __restrict__ foa,
                 const float* __restrict__ W1, const float* __restrict__ b1,
                 const short* __restrict__ W2b, float* __restrict__ out) {
  __shared__ short shH[64 * HSTR];           // H tile, bf16, 37.9 KB
  __shared__ float shSlab[CI * 3 * 130];     // reflect-padded input slab, 25 KB

  const int tid  = threadIdx.x;
  const int lane = tid & 63;
  const int wv   = tid >> 6;
  const int c15  = lane & 15;
  const int quad = lane >> 4;

  const int blk = blockIdx.x;
  const int b   = blk >> 8;
  const int rem = blk & 255;
  const int y   = rem >> 1;
  const int x0  = (rem & 1) << 6;

  const float fx  = foa[b * 2 + 0];
  const float fy  = foa[b * 2 + 1];
  const float dyv = (float)y - fy;

  const int ry0 = (y == 0) ? 1 : (y - 1);
  const int ry2 = (y == IMGH - 1) ? (IMGH - 2) : (y + 1);

  // ---- input slab: 16 ch x 3 rows x [1..128], cols 0/129 are x-reflections
  for (int e = tid; e < CI * 3 * IMGW; e += 256) {
    int xs = e & 127;
    int rowid = e >> 7;                 // 0..47
    int i = rowid / 3, r = rowid - (rowid / 3) * 3;
    int ryr = (r == 0) ? ry0 : ((r == 1) ? y : ry2);
    shSlab[(i * 3 + r) * 130 + 1 + xs] =
        in[((b * CI + i) * IMGH + ryr) * IMGW + xs];
  }
  if (tid < CI * 3) {
    int i = tid / 3, r = tid - (tid / 3) * 3;
    int ryr = (r == 0) ? ry0 : ((r == 1) ? y : ry2);
    const float* src = &in[((b * CI + i) * IMGH + ryr) * IMGW];
    shSlab[(i * 3 + r) * 130 + 0]   = src[1];     // reflect(x=-1) -> 1
    shSlab[(i * 3 + r) * 130 + 129] = src[126];   // reflect(x=128) -> 126
  }

  // ---- H tile: h[row][k] = relu(dx*W1[0,k] + dy*W1[1,k] + b1[k]); k==256 -> 1
  for (int g = tid; g < 64 * (KPAD / 8); g += 256) {   // 2304 groups of 8 k
    int row = g / 36;
    int k0  = (g - row * 36) * 8;
    float dxv = (float)(x0 + row) - fx;
    short hv[8];
    if (k0 < HID) {
      #pragma unroll
      for (int j = 0; j < 8; ++j) {
        int k = k0 + j;
        float h = fmaxf(fmaf(dxv, W1[k], fmaf(dyv, W1[HID + k], b1[k])), 0.f);
        hv[j] = f2bf(h);
      }
    } else {
      #pragma unroll
      for (int j = 0; j < 8; ++j) hv[j] = (k0 + j == HID) ? f2bf(1.f) : (short)0;
    }
    *(bf16x8*)&shH[row * HSTR + k0] = *(bf16x8*)hv;
  }
  __syncthreads();

  // ---- main loop: 4 output channels per wave, N split 5+4
  for (int oj = 0; oj < 4; ++oj) {
    const int o = wv + oj * 4;
    // per-lane base; frag f (= kk*9+nt) lives at Bl + f*512 (shorts)
    const short* Bl = W2b + (size_t)o * (NKK * NCH * 32) + (c15 << 5) + quad * 8;

    float P[16];
    #pragma unroll
    for (int t = 0; t < 16; ++t) P[t] = 0.f;

    gemm_half<0, 5>(Bl, shH, shSlab, P, c15, quad, x0);
    gemm_half<5, 4>(Bl, shH, shSlab, P, c15, quad, x0);

    // reduce-scatter across the 16-lane column group:
    // after the loop, P[0] at lane = sum over group of original P[c15]
    #pragma unroll
    for (int m = 8; m >= 1; m >>= 1) {
      const bool hi = (c15 & m) != 0;
      #pragma unroll
      for (int j = 0; j < m; ++j) {
        float keep = hi ? P[j + m] : P[j];
        float send = hi ? P[j] : P[j + m];
        float recv = __shfl_xor(send, m, 64);
        P[j] = keep + recv;
      }
    }

    const int x = x0 + (c15 >> 2) * 16 + quad * 4 + (c15 & 3);
    out[((b * CO + o) * IMGH + y) * IMGW + x] = P[0];
  }
}

// ---------------------------------------------------------------------------
extern "C" void kernel_launch(void* const* d_in, const int* in_sizes, int n_in,
                              void* d_out, int out_size, void* d_ws, size_t ws_size,
                              hipStream_t stream) {
  const float* in  = (const float*)d_in[0];   // [4,16,128,128]
  const float* foa = (const float*)d_in[1];   // [4,2]
  const float* W1  = (const float*)d_in[2];   // [2,256]
  const float* b1  = (const float*)d_in[3];   // [256]
  const float* W2  = (const float*)d_in[4];   // [256,2304]
  const float* b2  = (const float*)d_in[5];   // [2304]
  float* out = (float*)d_out;
  short* W2b = (short*)d_ws;                  // 16*9*144*32 bf16 = 1.33 MB

  prep_w2<<<324, 256, 0, stream>>>(W2, b2, W2b);
  ngconv_main<<<1024, 256, 0, stream>>>(in, foa, W1, b1, W2b, out);
}

// Round 4
// 419.051 us; speedup vs baseline: 1.1470x; 1.1470x over previous
//
#include <hip/hip_runtime.h>

// Problem constants (fixed by reference)
#define CI    16
#define CO    16
#define TAPS  9      // 3x3
#define HID   256
#define KPAD  288    // 256 + 32; k==256 row carries b2, k>256 zero
#define NKK   9      // KPAD/32 MFMA K-steps
#define NCH   144    // CI*TAPS columns per output channel
#define IMGH  128
#define IMGW  128
#define HSTR  296    // shH row stride (288 + 8 bf16 pad -> <=2-way LDS conflicts)

typedef float f32x4  __attribute__((ext_vector_type(4)));
typedef short bf16x8 __attribute__((ext_vector_type(8)));

__device__ __host__ __forceinline__ short f2bf(float f) {
  union { float f; unsigned u; } c; c.f = f;
  unsigned b = c.u + 0x7FFFu + ((c.u >> 16) & 1u);   // RNE
  return (short)(b >> 16);
}

// ---------------------------------------------------------------------------
// Prep: W2 [256][2304] fp32 (+ b2[2304]) -> W2b [o][kk][n:144][k:32] bf16,
// K padded to 288 (row 256 = b2, rows 257..287 = 0).
// ---------------------------------------------------------------------------
__global__ void prep_w2(const float* __restrict__ W2, const float* __restrict__ b2,
                        short* __restrict__ W2b) {
  __shared__ float tile[32][65];
  const int kk = blockIdx.x % NKK;
  const int colbase = (blockIdx.x / NKK) * 64;
  const int tid = threadIdx.x;

  for (int e = tid; e < 2048; e += 256) {
    int klr = e >> 6;          // 0..31
    int cc  = e & 63;
    int col = colbase + cc;
    float v;
    if (kk < 8) v = W2[(kk * 32 + klr) * (CO * NCH) + col];
    else        v = (klr == 0) ? b2[col] : 0.f;
    tile[klr][cc] = v;
  }
  __syncthreads();
  for (int e = tid; e < 2048; e += 256) {
    int cc = e >> 5;           // 0..63
    int kl = e & 31;
    int col = colbase + cc;
    int o = col / NCH;
    int n = col - o * NCH;
    W2b[(((o * NKK + kk) * NCH + n) << 5) + kl] = f2bf(tile[kl][cc]);
  }
}

// ---------------------------------------------------------------------------
// One N-slice of the per-channel GEMM: n-tiles [NB, NB+NC).
// kk loop is FORCIBLY not unrolled (#pragma unroll 1): with full unroll the
// compiler hoists up to 45 independent B-loads -> ~360 regs of load results
// -> scratch spill (the 290 MB WRITE_SIZE seen in rounds 1-3). One-iteration
// window keeps live regs ~200 < 256.
// ---------------------------------------------------------------------------
template<int NB, int NC>
__device__ __forceinline__ void gemm_slice(const short* __restrict__ Bl,
                                           const short* shHp,
                                           const float* shSlab,
                                           float* P,
                                           int c15, int quad, int x0) {
  f32x4 acc[4][NC];
  #pragma unroll
  for (int ms = 0; ms < 4; ++ms)
    #pragma unroll
    for (int j = 0; j < NC; ++j)
      acc[ms][j] = (f32x4){0.f, 0.f, 0.f, 0.f};

  #pragma unroll 1
  for (int kk = 0; kk < NKK; ++kk) {
    // batch-load this iteration's B fragments (issue early, wait once)
    bf16x8 bfr[NC];
    #pragma unroll
    for (int j = 0; j < NC; ++j)
      bfr[j] = *(const bf16x8*)&Bl[(kk * 9 + NB + j) << 9];
    bf16x8 af[4];
    #pragma unroll
    for (int ms = 0; ms < 4; ++ms)   // A: rows = pixels, ds_read_b128
      af[ms] = *(const bf16x8*)&shHp[(ms * 16 + c15) * HSTR + kk * 32 + quad * 8];
    #pragma unroll
    for (int j = 0; j < NC; ++j)
      #pragma unroll
      for (int ms = 0; ms < 4; ++ms)
        acc[ms][j] = __builtin_amdgcn_mfma_f32_16x16x32_bf16(
            af[ms], bfr[j], acc[ms][j], 0, 0, 0);
  }

  // partial epilogue: contract this slice's columns with the patch slab
  #pragma unroll
  for (int j = 0; j < NC; ++j) {
    int n15 = (NB + j) * 16 + c15;    // 0..143
    int i = n15 / 9;
    int q = n15 - i * 9;              // tap: dyr = q/3, dx = q%3
    int dyr = q / 3;
    int poff = (i * 3 + dyr) * 130 + (q - dyr * 3) + x0 + quad * 4;
    #pragma unroll
    for (int ms = 0; ms < 4; ++ms)
      #pragma unroll
      for (int r = 0; r < 4; ++r)
        P[ms * 4 + r] = fmaf(acc[ms][j][r], shSlab[poff + ms * 16 + r], P[ms * 4 + r]);
  }
}

// ---------------------------------------------------------------------------
// Main fused kernel. One block = 64 consecutive pixels of one image row.
// 4 waves; wave w computes output channels {w, w+4, w+8, w+12} for all 64
// pixels via MFMA 16x16x32 bf16 (M=pixels, N=144 per channel, K=288).
// N split 5+4 across two K-loop passes to keep acc <= 80 regs.
// grid = 4 batches * 128 rows * 2 half-rows = 1024 blocks x 256 threads.
// ---------------------------------------------------------------------------
__global__ __launch_bounds__(256, 2)
void ngconv_main(const float* __restrict__ in, const float* __restrict__ foa,
                 const float* __restrict__ W1, const float* __restrict__ b1,
                 const short* __restrict__ W2b, float* __restrict__ out) {
  __shared__ short shH[64 * HSTR];           // H tile, bf16, 37.9 KB
  __shared__ float shSlab[CI * 3 * 130];     // reflect-padded input slab, 25 KB

  const int tid  = threadIdx.x;
  const int lane = tid & 63;
  const int wv   = tid >> 6;
  const int c15  = lane & 15;
  const int quad = lane >> 4;

  const int blk = blockIdx.x;
  const int b   = blk >> 8;
  const int rem = blk & 255;
  const int y   = rem >> 1;
  const int x0  = (rem & 1) << 6;

  const float fx  = foa[b * 2 + 0];
  const float fy  = foa[b * 2 + 1];
  const float dyv = (float)y - fy;

  const int ry0 = (y == 0) ? 1 : (y - 1);
  const int ry2 = (y == IMGH - 1) ? (IMGH - 2) : (y + 1);

  // ---- input slab: 16 ch x 3 rows x [1..128], cols 0/129 are x-reflections
  for (int e = tid; e < CI * 3 * IMGW; e += 256) {
    int xs = e & 127;
    int rowid = e >> 7;                 // 0..47
    int i = rowid / 3, r = rowid - (rowid / 3) * 3;
    int ryr = (r == 0) ? ry0 : ((r == 1) ? y : ry2);
    shSlab[(i * 3 + r) * 130 + 1 + xs] =
        in[((b * CI + i) * IMGH + ryr) * IMGW + xs];
  }
  if (tid < CI * 3) {
    int i = tid / 3, r = tid - (tid / 3) * 3;
    int ryr = (r == 0) ? ry0 : ((r == 1) ? y : ry2);
    const float* src = &in[((b * CI + i) * IMGH + ryr) * IMGW];
    shSlab[(i * 3 + r) * 130 + 0]   = src[1];     // reflect(x=-1) -> 1
    shSlab[(i * 3 + r) * 130 + 129] = src[126];   // reflect(x=128) -> 126
  }

  // ---- H tile: h[row][k] = relu(dx*W1[0,k] + dy*W1[1,k] + b1[k]); k==256 -> 1
  for (int g = tid; g < 64 * (KPAD / 8); g += 256) {   // 2304 groups of 8 k
    int row = g / 36;
    int k0  = (g - row * 36) * 8;
    float dxv = (float)(x0 + row) - fx;
    short hv[8];
    if (k0 < HID) {
      #pragma unroll
      for (int j = 0; j < 8; ++j) {
        int k = k0 + j;
        float h = fmaxf(fmaf(dxv, W1[k], fmaf(dyv, W1[HID + k], b1[k])), 0.f);
        hv[j] = f2bf(h);
      }
    } else {
      #pragma unroll
      for (int j = 0; j < 8; ++j) hv[j] = (k0 + j == HID) ? f2bf(1.f) : (short)0;
    }
    *(bf16x8*)&shH[row * HSTR + k0] = *(bf16x8*)hv;
  }
  __syncthreads();

  // ---- main loop: 4 output channels per wave, N split 5+4
  #pragma unroll 1
  for (int oj = 0; oj < 4; ++oj) {
    const int o = wv + oj * 4;
    // per-lane base; frag f (= kk*9+nt) lives at Bl + f*512 (shorts)
    const short* Bl = W2b + (size_t)o * (NKK * NCH * 32) + (c15 << 5) + quad * 8;

    float P[16];
    #pragma unroll
    for (int t = 0; t < 16; ++t) P[t] = 0.f;

    gemm_slice<0, 5>(Bl, shH, shSlab, P, c15, quad, x0);
    gemm_slice<5, 4>(Bl, shH, shSlab, P, c15, quad, x0);

    // reduce-scatter across the 16-lane column group:
    // after the loop, P[0] at lane = sum over group of original P[c15]
    #pragma unroll
    for (int m = 8; m >= 1; m >>= 1) {
      const bool hi = (c15 & m) != 0;
      #pragma unroll
      for (int j = 0; j < m; ++j) {
        float keep = hi ? P[j + m] : P[j];
        float send = hi ? P[j] : P[j + m];
        float recv = __shfl_xor(send, m, 64);
        P[j] = keep + recv;
      }
    }

    const int x = x0 + (c15 >> 2) * 16 + quad * 4 + (c15 & 3);
    out[((b * CO + o) * IMGH + y) * IMGW + x] = P[0];
  }
}

// ---------------------------------------------------------------------------
extern "C" void kernel_launch(void* const* d_in, const int* in_sizes, int n_in,
                              void* d_out, int out_size, void* d_ws, size_t ws_size,
                              hipStream_t stream) {
  const float* in  = (const float*)d_in[0];   // [4,16,128,128]
  const float* foa = (const float*)d_in[1];   // [4,2]
  const float* W1  = (const float*)d_in[2];   // [2,256]
  const float* b1  = (const float*)d_in[3];   // [256]
  const float* W2  = (const float*)d_in[4];   // [256,2304]
  const float* b2  = (const float*)d_in[5];   // [2304]
  float* out = (float*)d_out;
  short* W2b = (short*)d_ws;                  // 16*9*144*32 bf16 = 1.33 MB

  prep_w2<<<324, 256, 0, stream>>>(W2, b2, W2b);
  ngconv_main<<<1024, 256, 0, stream>>>(in, foa, W1, b1, W2b, out);
}

// Round 5
// 418.916 us; speedup vs baseline: 1.1474x; 1.0003x over previous
//
#include <hip/hip_runtime.h>

// Problem constants (fixed by reference)
#define CI    16
#define CO    16
#define TAPS  9      // 3x3
#define HID   256
#define KPAD  288    // 256 + 32; k==256 row carries b2, k>256 zero
#define NKK   9      // KPAD/32 MFMA K-steps
#define NCH   144    // CI*TAPS columns per output channel
#define IMGH  128
#define IMGW  128
#define HSTR  296    // shH row stride (288 + 8 bf16 pad -> <=2-way LDS conflicts)

typedef float f32x4  __attribute__((ext_vector_type(4)));
typedef short bf16x8 __attribute__((ext_vector_type(8)));

__device__ __host__ __forceinline__ short f2bf(float f) {
  union { float f; unsigned u; } c; c.f = f;
  unsigned b = c.u + 0x7FFFu + ((c.u >> 16) & 1u);   // RNE
  return (short)(b >> 16);
}

// ---------------------------------------------------------------------------
// Prep: W2 [256][2304] fp32 (+ b2[2304]) -> W2b [o][kk][n:144][k:32] bf16,
// K padded to 288 (row 256 = b2, rows 257..287 = 0).
// ---------------------------------------------------------------------------
__global__ void prep_w2(const float* __restrict__ W2, const float* __restrict__ b2,
                        short* __restrict__ W2b) {
  __shared__ float tile[32][65];
  const int kk = blockIdx.x % NKK;
  const int colbase = (blockIdx.x / NKK) * 64;
  const int tid = threadIdx.x;

  for (int e = tid; e < 2048; e += 256) {
    int klr = e >> 6;          // 0..31
    int cc  = e & 63;
    int col = colbase + cc;
    float v;
    if (kk < 8) v = W2[(kk * 32 + klr) * (CO * NCH) + col];
    else        v = (klr == 0) ? b2[col] : 0.f;
    tile[klr][cc] = v;
  }
  __syncthreads();
  for (int e = tid; e < 2048; e += 256) {
    int cc = e >> 5;           // 0..63
    int kl = e & 31;
    int col = colbase + cc;
    int o = col / NCH;
    int n = col - o * NCH;
    W2b[(((o * NKK + kk) * NCH + n) << 5) + kl] = f2bf(tile[kl][cc]);
  }
}

// ---------------------------------------------------------------------------
// One N-slice of the per-channel GEMM: n-tiles [NB, NB+NC).
// kk loop NOT unrolled (window = one iteration: NC B-frags + 4 A-frags live).
// ---------------------------------------------------------------------------
template<int NB, int NC>
__device__ __forceinline__ void gemm_slice(const short* __restrict__ Bl,
                                           const short* shHp,
                                           const float* shSlab,
                                           float* P,
                                           int c15, int quad, int x0) {
  f32x4 acc[4][NC];
  #pragma unroll
  for (int ms = 0; ms < 4; ++ms)
    #pragma unroll
    for (int j = 0; j < NC; ++j)
      acc[ms][j] = (f32x4){0.f, 0.f, 0.f, 0.f};

  #pragma unroll 1
  for (int kk = 0; kk < NKK; ++kk) {
    // batch-load this iteration's B fragments (issue early, wait once)
    bf16x8 bfr[NC];
    #pragma unroll
    for (int j = 0; j < NC; ++j)
      bfr[j] = *(const bf16x8*)&Bl[(kk * 9 + NB + j) << 9];
    bf16x8 af[4];
    #pragma unroll
    for (int ms = 0; ms < 4; ++ms)   // A: rows = pixels, ds_read_b128
      af[ms] = *(const bf16x8*)&shHp[(ms * 16 + c15) * HSTR + kk * 32 + quad * 8];
    #pragma unroll
    for (int j = 0; j < NC; ++j)
      #pragma unroll
      for (int ms = 0; ms < 4; ++ms)
        acc[ms][j] = __builtin_amdgcn_mfma_f32_16x16x32_bf16(
            af[ms], bfr[j], acc[ms][j], 0, 0, 0);
  }

  // partial epilogue: contract this slice's columns with the patch slab
  #pragma unroll
  for (int j = 0; j < NC; ++j) {
    int n15 = (NB + j) * 16 + c15;    // 0..143
    int i = n15 / 9;
    int q = n15 - i * 9;              // tap: dyr = q/3, dx = q%3
    int dyr = q / 3;
    int poff = (i * 3 + dyr) * 130 + (q - dyr * 3) + x0 + quad * 4;
    #pragma unroll
    for (int ms = 0; ms < 4; ++ms)
      #pragma unroll
      for (int r = 0; r < 4; ++r)
        P[ms * 4 + r] = fmaf(acc[ms][j][r], shSlab[poff + ms * 16 + r], P[ms * 4 + r]);
  }
}

// ---------------------------------------------------------------------------
// Main fused kernel. One block = 64 consecutive pixels of one image row.
// 4 waves; wave w computes output channels {w, w+4, w+8, w+12} for all 64
// pixels via MFMA 16x16x32 bf16 (M=pixels, N=144 per channel, K=288).
// N split 5+4 across two K-loop passes to keep acc <= 80 regs.
//
// amdgpu_waves_per_eu(2,2): LDS (63 KB) caps residency at 2 blocks/CU =
// 2 waves/EU, but the allocator's default heuristic targets 4 waves/EU =
// 128 VGPRs (observed pinned VGPR_Count=128 across 4 structurally different
// kernels -> ~120 MB/dispatch scratch spill). Pinning min=max=2 gives the
// full 256-reg unified budget, which the live set (~200) fits.
// grid = 4 batches * 128 rows * 2 half-rows = 1024 blocks x 256 threads.
// ---------------------------------------------------------------------------
__global__ __attribute__((amdgpu_flat_work_group_size(256, 256),
                          amdgpu_waves_per_eu(2, 2)))
void ngconv_main(const float* __restrict__ in, const float* __restrict__ foa,
                 const float* __restrict__ W1, const float* __restrict__ b1,
                 const short* __restrict__ W2b, float* __restrict__ out) {
  __shared__ short shH[64 * HSTR];           // H tile, bf16, 37.9 KB
  __shared__ float shSlab[CI * 3 * 130];     // reflect-padded input slab, 25 KB

  const int tid  = threadIdx.x;
  const int lane = tid & 63;
  const int wv   = tid >> 6;
  const int c15  = lane & 15;
  const int quad = lane >> 4;

  const int blk = blockIdx.x;
  const int b   = blk >> 8;
  const int rem = blk & 255;
  const int y   = rem >> 1;
  const int x0  = (rem & 1) << 6;

  const float fx  = foa[b * 2 + 0];
  const float fy  = foa[b * 2 + 1];
  const float dyv = (float)y - fy;

  const int ry0 = (y == 0) ? 1 : (y - 1);
  const int ry2 = (y == IMGH - 1) ? (IMGH - 2) : (y + 1);

  // ---- input slab: 16 ch x 3 rows x [1..128], cols 0/129 are x-reflections
  for (int e = tid; e < CI * 3 * IMGW; e += 256) {
    int xs = e & 127;
    int rowid = e >> 7;                 // 0..47
    int i = rowid / 3, r = rowid - (rowid / 3) * 3;
    int ryr = (r == 0) ? ry0 : ((r == 1) ? y : ry2);
    shSlab[(i * 3 + r) * 130 + 1 + xs] =
        in[((b * CI + i) * IMGH + ryr) * IMGW + xs];
  }
  if (tid < CI * 3) {
    int i = tid / 3, r = tid - (tid / 3) * 3;
    int ryr = (r == 0) ? ry0 : ((r == 1) ? y : ry2);
    const float* src = &in[((b * CI + i) * IMGH + ryr) * IMGW];
    shSlab[(i * 3 + r) * 130 + 0]   = src[1];     // reflect(x=-1) -> 1
    shSlab[(i * 3 + r) * 130 + 129] = src[126];   // reflect(x=128) -> 126
  }

  // ---- H tile: h[row][k] = relu(dx*W1[0,k] + dy*W1[1,k] + b1[k]); k==256 -> 1
  for (int g = tid; g < 64 * (KPAD / 8); g += 256) {   // 2304 groups of 8 k
    int row = g / 36;
    int k0  = (g - row * 36) * 8;
    float dxv = (float)(x0 + row) - fx;
    short hv[8];
    if (k0 < HID) {
      #pragma unroll
      for (int j = 0; j < 8; ++j) {
        int k = k0 + j;
        float h = fmaxf(fmaf(dxv, W1[k], fmaf(dyv, W1[HID + k], b1[k])), 0.f);
        hv[j] = f2bf(h);
      }
    } else {
      #pragma unroll
      for (int j = 0; j < 8; ++j) hv[j] = (k0 + j == HID) ? f2bf(1.f) : (short)0;
    }
    *(bf16x8*)&shH[row * HSTR + k0] = *(bf16x8*)hv;
  }
  __syncthreads();

  // ---- main loop: 4 output channels per wave, N split 5+4
  #pragma unroll 1
  for (int oj = 0; oj < 4; ++oj) {
    const int o = wv + oj * 4;
    // per-lane base; frag f (= kk*9+nt) lives at Bl + f*512 (shorts)
    const short* Bl = W2b + (size_t)o * (NKK * NCH * 32) + (c15 << 5) + quad * 8;

    float P[16];
    #pragma unroll
    for (int t = 0; t < 16; ++t) P[t] = 0.f;

    gemm_slice<0, 5>(Bl, shH, shSlab, P, c15, quad, x0);
    gemm_slice<5, 4>(Bl, shH, shSlab, P, c15, quad, x0);

    // reduce-scatter across the 16-lane column group:
    // after the loop, P[0] at lane = sum over group of original P[c15]
    #pragma unroll
    for (int m = 8; m >= 1; m >>= 1) {
      const bool hi = (c15 & m) != 0;
      #pragma unroll
      for (int j = 0; j < m; ++j) {
        float keep = hi ? P[j + m] : P[j];
        float send = hi ? P[j] : P[j + m];
        float recv = __shfl_xor(send, m, 64);
        P[j] = keep + recv;
      }
    }

    const int x = x0 + (c15 >> 2) * 16 + quad * 4 + (c15 & 3);
    out[((b * CO + o) * IMGH + y) * IMGW + x] = P[0];
  }
}

// ---------------------------------------------------------------------------
extern "C" void kernel_launch(void* const* d_in, const int* in_sizes, int n_in,
                              void* d_out, int out_size, void* d_ws, size_t ws_size,
                              hipStream_t stream) {
  const float* in  = (const float*)d_in[0];   // [4,16,128,128]
  const float* foa = (const float*)d_in[1];   // [4,2]
  const float* W1  = (const float*)d_in[2];   // [2,256]
  const float* b1  = (const float*)d_in[3];   // [256]
  const float* W2  = (const float*)d_in[4];   // [256,2304]
  const float* b2  = (const float*)d_in[5];   // [2304]
  float* out = (float*)d_out;
  short* W2b = (short*)d_ws;                  // 16*9*144*32 bf16 = 1.33 MB

  prep_w2<<<324, 256, 0, stream>>>(W2, b2, W2b);
  ngconv_main<<<1024, 256, 0, stream>>>(in, foa, W1, b1, W2b, out);
}

// Round 6
// 324.308 us; speedup vs baseline: 1.4821x; 1.2917x over previous
//
#include <hip/hip_runtime.h>

// Problem constants (fixed by reference)
#define CI    16
#define CO    16
#define TAPS  9      // 3x3
#define HID   256
#define KPAD  288    // 256 + 32; k==256 row carries b2, k>256 zero
#define NKK   9      // KPAD/32 MFMA K-steps
#define NCH   144    // CI*TAPS columns per output channel
#define IMGH  128
#define IMGW  128
#define HSTR  296    // shH row stride (288 + 8 bf16 pad -> <=2-way LDS conflicts)

typedef float f32x4  __attribute__((ext_vector_type(4)));
typedef short bf16x8 __attribute__((ext_vector_type(8)));

__device__ __host__ __forceinline__ short f2bf(float f) {
  union { float f; unsigned u; } c; c.f = f;
  unsigned b = c.u + 0x7FFFu + ((c.u >> 16) & 1u);   // RNE
  return (short)(b >> 16);
}

// ---------------------------------------------------------------------------
// Prep: W2 [256][2304] fp32 (+ b2[2304]) -> W2b [o][kk][n:144][k:32] bf16,
// K padded to 288 (row 256 = b2, rows 257..287 = 0).
// ---------------------------------------------------------------------------
__global__ void prep_w2(const float* __restrict__ W2, const float* __restrict__ b2,
                        short* __restrict__ W2b) {
  __shared__ float tile[32][65];
  const int kk = blockIdx.x % NKK;
  const int colbase = (blockIdx.x / NKK) * 64;
  const int tid = threadIdx.x;

  for (int e = tid; e < 2048; e += 256) {
    int klr = e >> 6;          // 0..31
    int cc  = e & 63;
    int col = colbase + cc;
    float v;
    if (kk < 8) v = W2[(kk * 32 + klr) * (CO * NCH) + col];
    else        v = (klr == 0) ? b2[col] : 0.f;
    tile[klr][cc] = v;
  }
  __syncthreads();
  for (int e = tid; e < 2048; e += 256) {
    int cc = e >> 5;           // 0..63
    int kl = e & 31;
    int col = colbase + cc;
    int o = col / NCH;
    int n = col - o * NCH;
    W2b[(((o * NKK + kk) * NCH + n) << 5) + kl] = f2bf(tile[kl][cc]);
  }
}

// ---------------------------------------------------------------------------
// One N-pass of the per-channel GEMM: n-tiles [NB, NB+3).
// Live-set budget (the whole point): the allocator pins this kernel at 128
// unified VGPR+AGPR regs and ignores waves_per_eu hints (R1-R5 evidence:
// VGPR_Count==128 invariant, ~120 MB scratch writes). This pass keeps
// acc(48) + bfr(24) + af(8..32) + P(16) + misc(~15) ~= 111..135 regs.
// kk loop NOT unrolled (R4: halved spill by capping the hoist window).
// ---------------------------------------------------------------------------
template<int NB>
__device__ __forceinline__ void gemm_pass3(const short* __restrict__ Bl,
                                           const short* shHbase,
                                           const float* shSlab,
                                           float* P,
                                           int c15, int quad, int x0) {
  f32x4 acc[4][3];
  #pragma unroll
  for (int ms = 0; ms < 4; ++ms)
    #pragma unroll
    for (int j = 0; j < 3; ++j)
      acc[ms][j] = (f32x4){0.f, 0.f, 0.f, 0.f};

  #pragma unroll 1
  for (int kk = 0; kk < NKK; ++kk) {
    bf16x8 bfr[3];
    #pragma unroll
    for (int j = 0; j < 3; ++j)
      bfr[j] = *(const bf16x8*)&Bl[(kk * 9 + NB + j) << 9];
    #pragma unroll
    for (int ms = 0; ms < 4; ++ms) {
      bf16x8 af = *(const bf16x8*)&shHbase[ms * 16 * HSTR + kk * 32];
      #pragma unroll
      for (int j = 0; j < 3; ++j)
        acc[ms][j] = __builtin_amdgcn_mfma_f32_16x16x32_bf16(
            af, bfr[j], acc[ms][j], 0, 0, 0);
    }
  }

  // partial epilogue: contract this pass's columns with the patch slab
  #pragma unroll
  for (int j = 0; j < 3; ++j) {
    int n15 = (NB + j) * 16 + c15;    // 0..143
    int i = n15 / 9;
    int q = n15 - i * 9;              // tap: dyr = q/3, dx = q%3
    int dyr = q / 3;
    int poff = (i * 3 + dyr) * 130 + (q - dyr * 3) + x0 + quad * 4;
    #pragma unroll
    for (int ms = 0; ms < 4; ++ms)
      #pragma unroll
      for (int r = 0; r < 4; ++r)
        P[ms * 4 + r] = fmaf(acc[ms][j][r], shSlab[poff + ms * 16 + r], P[ms * 4 + r]);
  }
}

// ---------------------------------------------------------------------------
// Main fused kernel. One block = 64 consecutive pixels of one image row.
// 4 waves; wave w computes output channels {w, w+4, w+8, w+12} for all 64
// pixels via MFMA 16x16x32 bf16 (M=pixels, N=144 per channel, K=288).
// N split into three passes of 3 n-tiles to fit the 128-reg budget.
// grid = 4 batches * 128 rows * 2 half-rows = 1024 blocks x 256 threads.
// ---------------------------------------------------------------------------
__global__ __attribute__((amdgpu_flat_work_group_size(256, 256),
                          amdgpu_waves_per_eu(2, 2)))
void ngconv_main(const float* __restrict__ in, const float* __restrict__ foa,
                 const float* __restrict__ W1, const float* __restrict__ b1,
                 const short* __restrict__ W2b, float* __restrict__ out) {
  __shared__ short shH[64 * HSTR];           // H tile, bf16, 37.9 KB
  __shared__ float shSlab[CI * 3 * 130];     // reflect-padded input slab, 25 KB

  const int tid  = threadIdx.x;
  const int lane = tid & 63;
  const int wv   = tid >> 6;
  const int c15  = lane & 15;
  const int quad = lane >> 4;

  const int blk = blockIdx.x;
  const int b   = blk >> 8;
  const int rem = blk & 255;
  const int y   = rem >> 1;
  const int x0  = (rem & 1) << 6;

  const float fx  = foa[b * 2 + 0];
  const float fy  = foa[b * 2 + 1];
  const float dyv = (float)y - fy;

  const int ry0 = (y == 0) ? 1 : (y - 1);
  const int ry2 = (y == IMGH - 1) ? (IMGH - 2) : (y + 1);

  // ---- input slab: 16 ch x 3 rows x [1..128], cols 0/129 are x-reflections
  for (int e = tid; e < CI * 3 * IMGW; e += 256) {
    int xs = e & 127;
    int rowid = e >> 7;                 // 0..47
    int i = rowid / 3, r = rowid - (rowid / 3) * 3;
    int ryr = (r == 0) ? ry0 : ((r == 1) ? y : ry2);
    shSlab[(i * 3 + r) * 130 + 1 + xs] =
        in[((b * CI + i) * IMGH + ryr) * IMGW + xs];
  }
  if (tid < CI * 3) {
    int i = tid / 3, r = tid - (tid / 3) * 3;
    int ryr = (r == 0) ? ry0 : ((r == 1) ? y : ry2);
    const float* src = &in[((b * CI + i) * IMGH + ryr) * IMGW];
    shSlab[(i * 3 + r) * 130 + 0]   = src[1];     // reflect(x=-1) -> 1
    shSlab[(i * 3 + r) * 130 + 129] = src[126];   // reflect(x=128) -> 126
  }

  // ---- H tile: h[row][k] = relu(dx*W1[0,k] + dy*W1[1,k] + b1[k]); k==256 -> 1
  for (int g = tid; g < 64 * (KPAD / 8); g += 256) {   // 2304 groups of 8 k
    int row = g / 36;
    int k0  = (g - row * 36) * 8;
    float dxv = (float)(x0 + row) - fx;
    short hv[8];
    if (k0 < HID) {
      #pragma unroll
      for (int j = 0; j < 8; ++j) {
        int k = k0 + j;
        float h = fmaxf(fmaf(dxv, W1[k], fmaf(dyv, W1[HID + k], b1[k])), 0.f);
        hv[j] = f2bf(h);
      }
    } else {
      #pragma unroll
      for (int j = 0; j < 8; ++j) hv[j] = (k0 + j == HID) ? f2bf(1.f) : (short)0;
    }
    *(bf16x8*)&shH[row * HSTR + k0] = *(bf16x8*)hv;
  }
  __syncthreads();

  const short* shHbase = &shH[c15 * HSTR + quad * 8];

  // ---- main loop: 4 output channels per wave, N in three passes of 3
  #pragma unroll 1
  for (int oj = 0; oj < 4; ++oj) {
    const int o = wv + oj * 4;
    // per-lane base; frag f (= kk*9+nt) lives at Bl + f*512 (shorts)
    const short* Bl = W2b + (size_t)o * (NKK * NCH * 32) + (c15 << 5) + quad * 8;

    float P[16];
    #pragma unroll
    for (int t = 0; t < 16; ++t) P[t] = 0.f;

    gemm_pass3<0>(Bl, shHbase, shSlab, P, c15, quad, x0);
    gemm_pass3<3>(Bl, shHbase, shSlab, P, c15, quad, x0);
    gemm_pass3<6>(Bl, shHbase, shSlab, P, c15, quad, x0);

    // reduce-scatter across the 16-lane column group:
    // after the loop, P[0] at lane = sum over group of original P[c15]
    #pragma unroll
    for (int m = 8; m >= 1; m >>= 1) {
      const bool hi = (c15 & m) != 0;
      #pragma unroll
      for (int j = 0; j < m; ++j) {
        float keep = hi ? P[j + m] : P[j];
        float send = hi ? P[j] : P[j + m];
        float recv = __shfl_xor(send, m, 64);
        P[j] = keep + recv;
      }
    }

    const int x = x0 + (c15 >> 2) * 16 + quad * 4 + (c15 & 3);
    out[((b * CO + o) * IMGH + y) * IMGW + x] = P[0];
  }
}

// ---------------------------------------------------------------------------
extern "C" void kernel_launch(void* const* d_in, const int* in_sizes, int n_in,
                              void* d_out, int out_size, void* d_ws, size_t ws_size,
                              hipStream_t stream) {
  const float* in  = (const float*)d_in[0];   // [4,16,128,128]
  const float* foa = (const float*)d_in[1];   // [4,2]
  const float* W1  = (const float*)d_in[2];   // [2,256]
  const float* b1  = (const float*)d_in[3];   // [256]
  const float* W2  = (const float*)d_in[4];   // [256,2304]
  const float* b2  = (const float*)d_in[5];   // [2304]
  float* out = (float*)d_out;
  short* W2b = (short*)d_ws;                  // 16*9*144*32 bf16 = 1.33 MB

  prep_w2<<<324, 256, 0, stream>>>(W2, b2, W2b);
  ngconv_main<<<1024, 256, 0, stream>>>(in, foa, W1, b1, W2b, out);
}